// Round 8
// baseline (270.014 us; speedup 1.0000x reference)
//
#include <hip/hip_runtime.h>
#include <math.h>

// Problem constants (MoEGate: B=4,T=4096,C=2048,E=64,K=8)
#define NTOK   16384
#define CDIM   2048
#define NEXP   64
#define TOPK   8
#define GBLK   1024          // fused kernel grid: 16 tokens per block
#define NWAVE  8             // waves per block (in-block k-split factor)

typedef _Float16 f16x8 __attribute__((ext_vector_type(8)));
typedef float    f32x4 __attribute__((ext_vector_type(4)));

// ============================================================================
// Kernel 1: pack W[64][2048] fp32 into f16 hi/lo images in MFMA B-fragment
// order. Entry t = ((s*4 + nt)*64 + lane): 8 f16 for (expert = nt*16+(lane&15),
// k = s*32 + (lane>>4)*8 + j). GEMM lane then loads one contiguous 16B chunk.
// ============================================================================
__global__ __launch_bounds__(256) void pack_w16_kernel(
    const float* __restrict__ W,
    _Float16* __restrict__ Wh, _Float16* __restrict__ Wl)
{
    int t    = blockIdx.x * 256 + threadIdx.x;   // 0..16383
    int lane = t & 63;
    int nt   = (t >> 6) & 3;
    int s    = t >> 8;                           // k32-step, 0..63
    int e    = nt * 16 + (lane & 15);
    int k    = s * 32 + (lane >> 4) * 8;
    const float* src = W + (size_t)e * CDIM + k;
    #pragma unroll
    for (int j = 0; j < 8; j++) {
        float x = src[j];
        _Float16 h = (_Float16)x;                // rte
        Wh[(size_t)t * 8 + j] = h;
        Wl[(size_t)t * 8 + j] = (_Float16)(x - (float)h);
    }
}

// One f16-split MFMA step: 32 k-elements, all 4 expert tiles (12 MFMAs).
__device__ __forceinline__ void mfma_step(
    const float4 v0, const float4 v1,
    const f16x8* __restrict__ bh, const f16x8* __restrict__ bl,
    f32x4* __restrict__ acc)
{
    float xr[8] = {v0.x, v0.y, v0.z, v0.w, v1.x, v1.y, v1.z, v1.w};
    f16x8 ah, al;
    #pragma unroll
    for (int j = 0; j < 8; j++) {
        _Float16 h = (_Float16)xr[j];
        ah[j] = h;
        al[j] = (_Float16)(xr[j] - (float)h);    // exact residual
    }
    #pragma unroll
    for (int nt = 0; nt < 4; nt++) {
        acc[nt] = __builtin_amdgcn_mfma_f32_16x16x32_f16(ah, bh[nt], acc[nt], 0, 0, 0);
        acc[nt] = __builtin_amdgcn_mfma_f32_16x16x32_f16(al, bh[nt], acc[nt], 0, 0, 0);
        acc[nt] = __builtin_amdgcn_mfma_f32_16x16x32_f16(ah, bl[nt], acc[nt], 0, 0, 0);
    }
}

// ============================================================================
// Kernel 2 (FUSED, 8-way in-block k-split): block = 8 waves x SAME 16 tokens;
// wave w covers k-slice [w*256, (w+1)*256) (8 s-steps). Grid = NTOK/16 = 1024
// blocks -> 4 blocks/CU x 8 waves = 32 waves/CU (design occupancy 100%; R7's
// 31% fixed by doubling waves/block). Partials meet in 32 KB LDS laid out
// sacc[wid][nt][lane] so every ds_write/read_b128 is lane-contiguous (R7's
// 594k bank conflicts came from lane-stride-64B staging). Wave 0 sums
// w-ascending, then the verified 16-lane shfl_xor top-8 epilogue (strict >,
// lowest index wins ties = JAX). ZERO global atomics.
// ============================================================================
__global__ __launch_bounds__(512, 8) void gate_fused_kernel(
    const float* __restrict__ x,       // [NTOK][CDIM]
    const _Float16* __restrict__ Wh,   // packed image, 256 KB (L2-hot)
    const _Float16* __restrict__ Wl,   // packed image, 256 KB (L2-hot)
    const int*   __restrict__ mask,    // [NTOK]
    const float* __restrict__ gbias,   // [NEXP]
    const float* __restrict__ ebias,   // [NEXP]
    float*       __restrict__ out,     // [2*NTOK*TOPK + 1]
    float*       __restrict__ blockcnt)// [GBLK][NEXP]
{
    __shared__ f32x4 sacc[NWAVE][4][64];   // [wave][nt][lane] — lane-contiguous
    __shared__ unsigned int cnt[NEXP];
    const int tid  = threadIdx.x;
    const int lane = tid & 63;
    const int wid  = tid >> 6;             // 0..7
    if (tid < NEXP) cnt[tid] = 0u;         // wave 0 inits; only wave 0 uses cnt

    const int tok0 = blockIdx.x * 16;
    const int col  = lane & 15;            // token row for A / expert col for C
    const int q    = lane >> 4;            // quad
    const float* xp = x + (size_t)(tok0 + col) * CDIM + wid * 256 + q * 8;
    const f16x8* bhp = (const f16x8*)Wh + (size_t)wid * 8 * 256 + lane;
    const f16x8* blp = (const f16x8*)Wl + (size_t)wid * 8 * 256 + lane;

    f32x4 acc[4];
    #pragma unroll
    for (int nt = 0; nt < 4; nt++) acc[nt] = (f32x4){0.f, 0.f, 0.f, 0.f};

    #pragma unroll 2
    for (int s = 0; s < 8; s++) {
        float4 v0 = *(const float4*)(xp + s * 32);
        float4 v1 = *(const float4*)(xp + s * 32 + 4);
        f16x8 bh[4], bl[4];
        #pragma unroll
        for (int nt = 0; nt < 4; nt++) {
            bh[nt] = bhp[s * 256 + nt * 64];
            bl[nt] = blp[s * 256 + nt * 64];
        }
        mfma_step(v0, v1, bh, bl, acc);
    }

    // ---- stage partial accumulators to LDS (conflict-free), wave 0 combines
    #pragma unroll
    for (int nt = 0; nt < 4; nt++) sacc[wid][nt][lane] = acc[nt];
    __syncthreads();

    if (wid == 0) {
        f32x4 zv[4];
        #pragma unroll
        for (int nt = 0; nt < 4; nt++) {
            f32x4 s = sacc[0][nt][lane];
            #pragma unroll
            for (int w = 1; w < NWAVE; w++) s += sacc[w][nt][lane];  // w-ascending
            zv[nt] = s;
        }

        float gb[4], eb[4];
        #pragma unroll
        for (int nt = 0; nt < 4; nt++) {
            gb[nt] = gbias[nt * 16 + col];
            eb[nt] = ebias[nt * 16 + col];
        }

        #pragma unroll
        for (int r = 0; r < 4; r++) {
            const int t = tok0 + q * 4 + r;     // C layout: row = q*4 + reg
            float z[4], sel[4];
            #pragma unroll
            for (int nt = 0; nt < 4; nt++) {
                z[nt]   = zv[nt][r] + gb[nt];
                sel[nt] = z[nt] + eb[nt];
            }

            int idxs[TOPK]; float probs[TOPK]; float psum = 0.f;
            #pragma unroll
            for (int rr = 0; rr < TOPK; rr++) {
                float bv = -INFINITY, bz = 0.f; int bidx = 1 << 30;
                #pragma unroll
                for (int nt = 0; nt < 4; nt++)
                    if (sel[nt] > bv) { bv = sel[nt]; bz = z[nt]; bidx = nt * 16 + col; }
                #pragma unroll
                for (int m = 1; m < 16; m <<= 1) {   // xor<16 stays in 16-lane group
                    float ov = __shfl_xor(bv, m);
                    float oz = __shfl_xor(bz, m);
                    int   oi = __shfl_xor(bidx, m);
                    if (ov > bv || (ov == bv && oi < bidx)) { bv = ov; bz = oz; bidx = oi; }
                }
                idxs[rr] = bidx;
                float p = 1.f / (1.f + expf(-bz));
                probs[rr] = p; psum += p;
                if ((bidx & 15) == col) sel[bidx >> 4] = -INFINITY;   // mark used
            }
            float inv = 1.f / psum;
            if (col < TOPK) {
                out[(size_t)t * TOPK + col] = (float)idxs[col];
                out[(size_t)NTOK * TOPK + (size_t)t * TOPK + col] = probs[col] * inv;
                if (mask[t] != 0) atomicAdd(&cnt[idxs[col]], 1u);
            }
        }
        blockcnt[(size_t)blockIdx.x * NEXP + lane] = (float)cnt[lane];
    }
}

// ============================================================================
// Kernel 3: tree-sum per-block counts -> maxvio. One block, 256 threads.
// ============================================================================
__global__ __launch_bounds__(256) void finalize_kernel(
    const float* __restrict__ blockcnt, float* __restrict__ out)
{
    __shared__ float ps[4][NEXP];
    const int t = threadIdx.x;
    const int e = t & 63, c = t >> 6;
    float s = 0.f;
    #pragma unroll 8
    for (int b = 0; b < GBLK / 4; b++)
        s += blockcnt[(size_t)(c * (GBLK / 4) + b) * NEXP + e];
    ps[c][e] = s;
    __syncthreads();
    if (t < 64) {
        float tot = ps[0][t] + ps[1][t] + ps[2][t] + ps[3][t];
        float mx = tot, sm = tot;
        #pragma unroll
        for (int o = 32; o > 0; o >>= 1) {
            mx = fmaxf(mx, __shfl_down(mx, o));
            sm += __shfl_down(sm, o);
        }
        if (t == 0) {
            float avg = sm / (float)NEXP;
            out[2 * NTOK * TOPK] = (mx - avg) / (avg + 1e-5f);
        }
    }
}

// ============================================================================
// Fallback for tiny workspace: R1 fused fp32 kernel (known-correct).
// ============================================================================
__global__ __launch_bounds__(256) void fused_fallback_kernel(
    const float* __restrict__ x, const int* __restrict__ mask,
    const float* __restrict__ W, const float* __restrict__ gbias,
    const float* __restrict__ ebias, float* __restrict__ out,
    unsigned int* __restrict__ counts)
{
    __shared__ float As[64][36];
    __shared__ float Bs[64][36];
    __shared__ float Lg[64][NEXP + 1];
    __shared__ float s_gb[NEXP], s_eb[NEXP];
    __shared__ unsigned int s_cnt[NEXP];
    const int tid = threadIdx.x;
    const int tx = tid & 15, ty = tid >> 4;
    const int m0 = blockIdx.x * 64;
    if (tid < NEXP) { s_gb[tid] = gbias[tid]; s_eb[tid] = ebias[tid]; s_cnt[tid] = 0u; }
    float acc[4][4] = {};
    for (int kb = 0; kb < CDIM; kb += 32) {
        __syncthreads();
        #pragma unroll
        for (int p = 0; p < 2; p++) {
            int lin = tid + p * 256; int m = lin >> 3; int c4 = (lin & 7) << 2;
            *(float4*)&As[m][c4] = *(const float4*)&x[(size_t)(m0 + m) * CDIM + kb + c4];
            *(float4*)&Bs[m][c4] = *(const float4*)&W[(size_t)m * CDIM + kb + c4];
        }
        __syncthreads();
        #pragma unroll
        for (int k4 = 0; k4 < 32; k4 += 4) {
            float4 a[4], b[4];
            #pragma unroll
            for (int i = 0; i < 4; i++) a[i] = *(const float4*)&As[ty * 4 + i][k4];
            #pragma unroll
            for (int j = 0; j < 4; j++) b[j] = *(const float4*)&Bs[tx * 4 + j][k4];
            #pragma unroll
            for (int i = 0; i < 4; i++)
                #pragma unroll
                for (int j = 0; j < 4; j++)
                    acc[i][j] += a[i].x * b[j].x + a[i].y * b[j].y
                               + a[i].z * b[j].z + a[i].w * b[j].w;
        }
    }
    __syncthreads();
    #pragma unroll
    for (int i = 0; i < 4; i++)
        #pragma unroll
        for (int j = 0; j < 4; j++)
            Lg[ty * 4 + i][tx * 4 + j] = acc[i][j] + s_gb[tx * 4 + j];
    __syncthreads();
    if (tid < 64) {
        const int g = m0 + tid;
        unsigned long long used = 0ull;
        int idxs[TOPK]; float probs[TOPK]; float psum = 0.f;
        #pragma unroll
        for (int k = 0; k < TOPK; k++) {
            float best = -INFINITY; int bi = 0;
            for (int n = 0; n < NEXP; n++) {
                if ((used >> n) & 1ull) continue;
                float vv = Lg[tid][n] + s_eb[n];
                if (vv > best) { best = vv; bi = n; }
            }
            used |= (1ull << bi);
            idxs[k] = bi;
            float p = 1.f / (1.f + expf(-Lg[tid][bi]));
            probs[k] = p; psum += p;
        }
        float inv = 1.f / psum;
        #pragma unroll
        for (int k = 0; k < TOPK; k++) {
            out[(size_t)g * TOPK + k] = (float)idxs[k];
            out[(size_t)NTOK * TOPK + (size_t)g * TOPK + k] = probs[k] * inv;
        }
        if (mask[g] != 0)
            #pragma unroll
            for (int k = 0; k < TOPK; k++) atomicAdd(&s_cnt[idxs[k]], 1u);
    }
    __syncthreads();
    if (tid < NEXP && s_cnt[tid] != 0u) atomicAdd(&counts[tid], s_cnt[tid]);
}

__global__ void finalize_atomic_kernel(const unsigned int* __restrict__ counts,
                                       float* __restrict__ out)
{
    const int t = threadIdx.x;
    float c  = (float)counts[t];
    float mx = c, sm = c;
    #pragma unroll
    for (int o = 32; o > 0; o >>= 1) {
        mx = fmaxf(mx, __shfl_down(mx, o));
        sm += __shfl_down(sm, o);
    }
    if (t == 0) {
        float avg = sm / (float)NEXP;
        out[2 * NTOK * TOPK] = (mx - avg) / (avg + 1e-5f);
    }
}

extern "C" void kernel_launch(void* const* d_in, const int* in_sizes, int n_in,
                              void* d_out, int out_size, void* d_ws, size_t ws_size,
                              hipStream_t stream)
{
    const float* x     = (const float*)d_in[0];
    const int*   mask  = (const int*)  d_in[1];
    const float* W     = (const float*)d_in[2];
    const float* gbias = (const float*)d_in[3];
    const float* ebias = (const float*)d_in[4];
    float* out = (float*)d_out;

    // ws layout: [Wh 256KB][Wl 256KB][blockcnt 256KB]
    const size_t whB  = (size_t)NEXP * CDIM * sizeof(_Float16);   // 256 KB
    const size_t bcB  = (size_t)GBLK * NEXP * sizeof(float);      // 256 KB
    const size_t need = 2 * whB + bcB;

    if (ws_size >= need) {
        _Float16* Wh = (_Float16*)d_ws;
        _Float16* Wl = (_Float16*)((char*)d_ws + whB);
        float* blockcnt = (float*)((char*)d_ws + 2 * whB);

        pack_w16_kernel<<<64, 256, 0, stream>>>(W, Wh, Wl);
        gate_fused_kernel<<<GBLK, 512, 0, stream>>>(x, Wh, Wl, mask, gbias, ebias, out, blockcnt);
        finalize_kernel<<<1, 256, 0, stream>>>(blockcnt, out);
        return;
    }

    // Fallback: fused fp32 kernel + global-atomic counts
    unsigned int* counts = (unsigned int*)d_ws;
    hipMemsetAsync(d_ws, 0, NEXP * sizeof(unsigned int), stream);
    fused_fallback_kernel<<<NTOK / 64, 256, 0, stream>>>(x, mask, W, gbias, ebias, out, counts);
    finalize_atomic_kernel<<<1, 64, 0, stream>>>(counts, out);
}

// Round 9
// 229.101 us; speedup vs baseline: 1.1786x; 1.1786x over previous
//
#include <hip/hip_runtime.h>
#include <math.h>

// Problem constants (MoEGate: B=4,T=4096,C=2048,E=64,K=8)
#define NTOK   16384
#define CDIM   2048
#define NEXP   64
#define TOPK   8
#define TOKB   32            // tokens per block (2 MFMA row-tiles)
#define NWAVE  8             // waves per block (in-block k-split factor)
#define GBLK   (NTOK / TOKB) // 512 blocks

typedef _Float16 f16x8 __attribute__((ext_vector_type(8)));
typedef float    f32x4 __attribute__((ext_vector_type(4)));

// ============================================================================
// Kernel 1: pack W[64][2048] fp32 into f16 hi/lo images in MFMA B-fragment
// order. Entry t = ((s*4 + nt)*64 + lane): 8 f16 for (expert = nt*16+(lane&15),
// k = s*32 + (lane>>4)*8 + j). GEMM lane then loads one contiguous 16B chunk.
// ============================================================================
__global__ __launch_bounds__(256) void pack_w16_kernel(
    const float* __restrict__ W,
    _Float16* __restrict__ Wh, _Float16* __restrict__ Wl)
{
    int t    = blockIdx.x * 256 + threadIdx.x;   // 0..16383
    int lane = t & 63;
    int nt   = (t >> 6) & 3;
    int s    = t >> 8;                           // k32-step, 0..63
    int e    = nt * 16 + (lane & 15);
    int k    = s * 32 + (lane >> 4) * 8;
    const float* src = W + (size_t)e * CDIM + k;
    #pragma unroll
    for (int j = 0; j < 8; j++) {
        float x = src[j];
        _Float16 h = (_Float16)x;                // rte
        Wh[(size_t)t * 8 + j] = h;
        Wl[(size_t)t * 8 + j] = (_Float16)(x - (float)h);
    }
}

__device__ __forceinline__ void split_f16(
    const float4 v0, const float4 v1, f16x8& ah, f16x8& al)
{
    float xr[8] = {v0.x, v0.y, v0.z, v0.w, v1.x, v1.y, v1.z, v1.w};
    #pragma unroll
    for (int j = 0; j < 8; j++) {
        _Float16 h = (_Float16)xr[j];
        ah[j] = h;
        al[j] = (_Float16)(xr[j] - (float)h);    // exact residual
    }
}

// ============================================================================
// Kernel 2 (FUSED): 8-way in-block k-split x 32-token row-tile.
// Block = 512 threads = 8 waves over the SAME 32 tokens; wave w covers
// k-slice [w*256,(w+1)*256) (8 s-steps). Each wave computes TWO 16-token
// A-tiles against shared B-frags: 24 MFMAs / 12 loads per s-step (R7 was
// 12/10) — halves B traffic, doubles ILP. __launch_bounds__(512,4) gives a
// 128-VGPR cap (R8's (512,8)=64-cap spilled acc to scratch: 38 MB scratch
// writes, dur 84->116). Grid 512 -> 2 blocks/CU x 8 waves = 16 waves/CU.
// Partials meet in 64 KB LDS (lane-contiguous, conflict-free); waves 0 and 1
// each reduce one tokenset (w-ascending = k-order, matching verified rounds)
// then run the verified 16-lane shfl_xor top-8 (strict >, lowest index wins
// ties = JAX). ZERO global atomics.
// ============================================================================
__global__ __launch_bounds__(512, 4) void gate_fused_kernel(
    const float* __restrict__ x,       // [NTOK][CDIM]
    const _Float16* __restrict__ Wh,   // packed image, 256 KB (L2-hot)
    const _Float16* __restrict__ Wl,   // packed image, 256 KB (L2-hot)
    const int*   __restrict__ mask,    // [NTOK]
    const float* __restrict__ gbias,   // [NEXP]
    const float* __restrict__ ebias,   // [NEXP]
    float*       __restrict__ out,     // [2*NTOK*TOPK + 1]
    float*       __restrict__ blockcnt)// [GBLK][NEXP]
{
    __shared__ f32x4 sacc[NWAVE][2][4][64];  // [wave][tokenset][nt][lane], 64 KB
    __shared__ unsigned int cnt[NEXP];
    const int tid  = threadIdx.x;
    const int lane = tid & 63;
    const int wid  = tid >> 6;               // 0..7
    if (tid < NEXP) cnt[tid] = 0u;

    const int tok0 = blockIdx.x * TOKB;
    const int col  = lane & 15;              // token row for A / expert col for C
    const int q    = lane >> 4;              // quad
    const float* xpA = x + (size_t)(tok0 + col) * CDIM + wid * 256 + q * 8;
    const float* xpB = xpA + (size_t)16 * CDIM;
    const f16x8* bhp = (const f16x8*)Wh + (size_t)wid * 8 * 256 + lane;
    const f16x8* blp = (const f16x8*)Wl + (size_t)wid * 8 * 256 + lane;

    f32x4 accA[4], accB[4];
    #pragma unroll
    for (int nt = 0; nt < 4; nt++) {
        accA[nt] = (f32x4){0.f, 0.f, 0.f, 0.f};
        accB[nt] = (f32x4){0.f, 0.f, 0.f, 0.f};
    }

    #pragma unroll 2
    for (int s = 0; s < 8; s++) {
        float4 a0 = *(const float4*)(xpA + s * 32);
        float4 a1 = *(const float4*)(xpA + s * 32 + 4);
        float4 c0 = *(const float4*)(xpB + s * 32);
        float4 c1 = *(const float4*)(xpB + s * 32 + 4);
        f16x8 bh[4], bl[4];
        #pragma unroll
        for (int nt = 0; nt < 4; nt++) {
            bh[nt] = bhp[s * 256 + nt * 64];
            bl[nt] = blp[s * 256 + nt * 64];
        }
        f16x8 ahA, alA, ahB, alB;
        split_f16(a0, a1, ahA, alA);
        split_f16(c0, c1, ahB, alB);
        #pragma unroll
        for (int nt = 0; nt < 4; nt++) {
            accA[nt] = __builtin_amdgcn_mfma_f32_16x16x32_f16(ahA, bh[nt], accA[nt], 0, 0, 0);
            accA[nt] = __builtin_amdgcn_mfma_f32_16x16x32_f16(alA, bh[nt], accA[nt], 0, 0, 0);
            accA[nt] = __builtin_amdgcn_mfma_f32_16x16x32_f16(ahA, bl[nt], accA[nt], 0, 0, 0);
            accB[nt] = __builtin_amdgcn_mfma_f32_16x16x32_f16(ahB, bh[nt], accB[nt], 0, 0, 0);
            accB[nt] = __builtin_amdgcn_mfma_f32_16x16x32_f16(alB, bh[nt], accB[nt], 0, 0, 0);
            accB[nt] = __builtin_amdgcn_mfma_f32_16x16x32_f16(ahB, bl[nt], accB[nt], 0, 0, 0);
        }
    }

    // ---- stage partial accumulators to LDS (lane-contiguous => conflict-free)
    #pragma unroll
    for (int nt = 0; nt < 4; nt++) {
        sacc[wid][0][nt][lane] = accA[nt];
        sacc[wid][1][nt][lane] = accB[nt];
    }
    __syncthreads();

    // ---- epilogue: wave 0 -> tokenset 0, wave 1 -> tokenset 1
    if (wid < 2) {
        const int ts = wid;
        f32x4 zv[4];
        #pragma unroll
        for (int nt = 0; nt < 4; nt++) {
            f32x4 s = sacc[0][ts][nt][lane];
            #pragma unroll
            for (int w = 1; w < NWAVE; w++) s += sacc[w][ts][nt][lane]; // k-order
            zv[nt] = s;
        }

        float gb[4], eb[4];
        #pragma unroll
        for (int nt = 0; nt < 4; nt++) {
            gb[nt] = gbias[nt * 16 + col];
            eb[nt] = ebias[nt * 16 + col];
        }

        #pragma unroll
        for (int r = 0; r < 4; r++) {
            const int t = tok0 + ts * 16 + q * 4 + r;   // C layout: row = q*4+reg
            float z[4], sel[4];
            #pragma unroll
            for (int nt = 0; nt < 4; nt++) {
                z[nt]   = zv[nt][r] + gb[nt];
                sel[nt] = z[nt] + eb[nt];
            }

            int idxs[TOPK]; float probs[TOPK]; float psum = 0.f;
            #pragma unroll
            for (int rr = 0; rr < TOPK; rr++) {
                float bv = -INFINITY, bz = 0.f; int bidx = 1 << 30;
                #pragma unroll
                for (int nt = 0; nt < 4; nt++)
                    if (sel[nt] > bv) { bv = sel[nt]; bz = z[nt]; bidx = nt * 16 + col; }
                #pragma unroll
                for (int m = 1; m < 16; m <<= 1) {   // xor<16 stays in 16-lane group
                    float ov = __shfl_xor(bv, m);
                    float oz = __shfl_xor(bz, m);
                    int   oi = __shfl_xor(bidx, m);
                    if (ov > bv || (ov == bv && oi < bidx)) { bv = ov; bz = oz; bidx = oi; }
                }
                idxs[rr] = bidx;
                float p = 1.f / (1.f + expf(-bz));
                probs[rr] = p; psum += p;
                if ((bidx & 15) == col) sel[bidx >> 4] = -INFINITY;   // mark used
            }
            float inv = 1.f / psum;
            if (col < TOPK) {
                out[(size_t)t * TOPK + col] = (float)idxs[col];
                out[(size_t)NTOK * TOPK + (size_t)t * TOPK + col] = probs[col] * inv;
                if (mask[t] != 0) atomicAdd(&cnt[idxs[col]], 1u);
            }
        }
    }
    __syncthreads();
    if (tid < NEXP)
        blockcnt[(size_t)blockIdx.x * NEXP + tid] = (float)cnt[tid];
}

// ============================================================================
// Kernel 3: tree-sum per-block counts -> maxvio. One block, 256 threads.
// ============================================================================
__global__ __launch_bounds__(256) void finalize_kernel(
    const float* __restrict__ blockcnt, float* __restrict__ out)
{
    __shared__ float ps[4][NEXP];
    const int t = threadIdx.x;
    const int e = t & 63, c = t >> 6;
    float s = 0.f;
    #pragma unroll 8
    for (int b = 0; b < GBLK / 4; b++)
        s += blockcnt[(size_t)(c * (GBLK / 4) + b) * NEXP + e];
    ps[c][e] = s;
    __syncthreads();
    if (t < 64) {
        float tot = ps[0][t] + ps[1][t] + ps[2][t] + ps[3][t];
        float mx = tot, sm = tot;
        #pragma unroll
        for (int o = 32; o > 0; o >>= 1) {
            mx = fmaxf(mx, __shfl_down(mx, o));
            sm += __shfl_down(sm, o);
        }
        if (t == 0) {
            float avg = sm / (float)NEXP;
            out[2 * NTOK * TOPK] = (mx - avg) / (avg + 1e-5f);
        }
    }
}

// ============================================================================
// Fallback for tiny workspace: R1 fused fp32 kernel (known-correct).
// ============================================================================
__global__ __launch_bounds__(256) void fused_fallback_kernel(
    const float* __restrict__ x, const int* __restrict__ mask,
    const float* __restrict__ W, const float* __restrict__ gbias,
    const float* __restrict__ ebias, float* __restrict__ out,
    unsigned int* __restrict__ counts)
{
    __shared__ float As[64][36];
    __shared__ float Bs[64][36];
    __shared__ float Lg[64][NEXP + 1];
    __shared__ float s_gb[NEXP], s_eb[NEXP];
    __shared__ unsigned int s_cnt[NEXP];
    const int tid = threadIdx.x;
    const int tx = tid & 15, ty = tid >> 4;
    const int m0 = blockIdx.x * 64;
    if (tid < NEXP) { s_gb[tid] = gbias[tid]; s_eb[tid] = ebias[tid]; s_cnt[tid] = 0u; }
    float acc[4][4] = {};
    for (int kb = 0; kb < CDIM; kb += 32) {
        __syncthreads();
        #pragma unroll
        for (int p = 0; p < 2; p++) {
            int lin = tid + p * 256; int m = lin >> 3; int c4 = (lin & 7) << 2;
            *(float4*)&As[m][c4] = *(const float4*)&x[(size_t)(m0 + m) * CDIM + kb + c4];
            *(float4*)&Bs[m][c4] = *(const float4*)&W[(size_t)m * CDIM + kb + c4];
        }
        __syncthreads();
        #pragma unroll
        for (int k4 = 0; k4 < 32; k4 += 4) {
            float4 a[4], b[4];
            #pragma unroll
            for (int i = 0; i < 4; i++) a[i] = *(const float4*)&As[ty * 4 + i][k4];
            #pragma unroll
            for (int j = 0; j < 4; j++) b[j] = *(const float4*)&Bs[tx * 4 + j][k4];
            #pragma unroll
            for (int i = 0; i < 4; i++)
                #pragma unroll
                for (int j = 0; j < 4; j++)
                    acc[i][j] += a[i].x * b[j].x + a[i].y * b[j].y
                               + a[i].z * b[j].z + a[i].w * b[j].w;
        }
    }
    __syncthreads();
    #pragma unroll
    for (int i = 0; i < 4; i++)
        #pragma unroll
        for (int j = 0; j < 4; j++)
            Lg[ty * 4 + i][tx * 4 + j] = acc[i][j] + s_gb[tx * 4 + j];
    __syncthreads();
    if (tid < 64) {
        const int g = m0 + tid;
        unsigned long long used = 0ull;
        int idxs[TOPK]; float probs[TOPK]; float psum = 0.f;
        #pragma unroll
        for (int k = 0; k < TOPK; k++) {
            float best = -INFINITY; int bi = 0;
            for (int n = 0; n < NEXP; n++) {
                if ((used >> n) & 1ull) continue;
                float vv = Lg[tid][n] + s_eb[n];
                if (vv > best) { best = vv; bi = n; }
            }
            used |= (1ull << bi);
            idxs[k] = bi;
            float p = 1.f / (1.f + expf(-Lg[tid][bi]));
            probs[k] = p; psum += p;
        }
        float inv = 1.f / psum;
        #pragma unroll
        for (int k = 0; k < TOPK; k++) {
            out[(size_t)g * TOPK + k] = (float)idxs[k];
            out[(size_t)NTOK * TOPK + (size_t)g * TOPK + k] = probs[k] * inv;
        }
        if (mask[g] != 0)
            #pragma unroll
            for (int k = 0; k < TOPK; k++) atomicAdd(&s_cnt[idxs[k]], 1u);
    }
    __syncthreads();
    if (tid < NEXP && s_cnt[tid] != 0u) atomicAdd(&counts[tid], s_cnt[tid]);
}

__global__ void finalize_atomic_kernel(const unsigned int* __restrict__ counts,
                                       float* __restrict__ out)
{
    const int t = threadIdx.x;
    float c  = (float)counts[t];
    float mx = c, sm = c;
    #pragma unroll
    for (int o = 32; o > 0; o >>= 1) {
        mx = fmaxf(mx, __shfl_down(mx, o));
        sm += __shfl_down(sm, o);
    }
    if (t == 0) {
        float avg = sm / (float)NEXP;
        out[2 * NTOK * TOPK] = (mx - avg) / (avg + 1e-5f);
    }
}

extern "C" void kernel_launch(void* const* d_in, const int* in_sizes, int n_in,
                              void* d_out, int out_size, void* d_ws, size_t ws_size,
                              hipStream_t stream)
{
    const float* x     = (const float*)d_in[0];
    const int*   mask  = (const int*)  d_in[1];
    const float* W     = (const float*)d_in[2];
    const float* gbias = (const float*)d_in[3];
    const float* ebias = (const float*)d_in[4];
    float* out = (float*)d_out;

    // ws layout: [Wh 256KB][Wl 256KB][blockcnt 128KB]
    const size_t whB  = (size_t)NEXP * CDIM * sizeof(_Float16);   // 256 KB
    const size_t bcB  = (size_t)GBLK * NEXP * sizeof(float);      // 128 KB
    const size_t need = 2 * whB + bcB;

    if (ws_size >= need) {
        _Float16* Wh = (_Float16*)d_ws;
        _Float16* Wl = (_Float16*)((char*)d_ws + whB);
        float* blockcnt = (float*)((char*)d_ws + 2 * whB);

        pack_w16_kernel<<<64, 256, 0, stream>>>(W, Wh, Wl);
        gate_fused_kernel<<<GBLK, 512, 0, stream>>>(x, Wh, Wl, mask, gbias, ebias, out, blockcnt);
        finalize_kernel<<<1, 256, 0, stream>>>(blockcnt, out);
        return;
    }

    // Fallback: fused fp32 kernel + global-atomic counts
    unsigned int* counts = (unsigned int*)d_ws;
    hipMemsetAsync(d_ws, 0, NEXP * sizeof(unsigned int), stream);
    fused_fallback_kernel<<<NTOK / 64, 256, 0, stream>>>(x, mask, W, gbias, ebias, out, counts);
    finalize_atomic_kernel<<<1, 64, 0, stream>>>(counts, out);
}